// Round 11
// baseline (170.504 us; speedup 1.0000x reference)
//
#include <hip/hip_runtime.h>

#define NB   64
#define NT   256
#define NI   512
#define NO   512
#define NOBS 128
#define ETA  0.01f

typedef __attribute__((ext_vector_type(8))) short bf16x8;
typedef __attribute__((ext_vector_type(4))) float f32x4;

#define X4_COUNT  (NB*NT*NI/4)
#define WG4_COUNT (NB*NOBS*NI/4)
#define K0_TOTAL  (X4_COUNT + WG4_COUNT)

__device__ __forceinline__ unsigned short f2bf(float f) {
    unsigned int u = __float_as_uint(f);
    return (unsigned short)((u + 0x7fffu + ((u >> 16) & 1u)) >> 16); // RNE
}

// ---------------- K0: X -> bf16 ; gather obs rows of W -> bf16 ----------------
__global__ __launch_bounds__(256)
void k0_convert(const float* __restrict__ X, const float* __restrict__ Wi,
                const int* __restrict__ obs,
                unsigned short* __restrict__ Xb, unsigned short* __restrict__ Wg)
{
    int idx = blockIdx.x * 256 + threadIdx.x;
    const int stride = gridDim.x * 256;
    for (; idx < K0_TOTAL; idx += stride) {
        float4 v; ushort4* dst;
        if (idx < X4_COUNT) {
            v = ((const float4*)X)[idx];
            dst = (ushort4*)Xb + idx;
        } else {
            int g = idx - X4_COUNT;
            int row = g >> 7, pos = g & 127;
            int b = row >> 7, j = row & 127;
            v = ((const float4*)(Wi + ((size_t)b * NO + obs[j]) * NI))[pos];
            dst = (ushort4*)Wg + ((size_t)row * 128 + pos);
        }
        *dst = make_ushort4(f2bf(v.x), f2bf(v.y), f2bf(v.z), f2bf(v.w));
    }
}

// ---------------- K1: LDS-tiled bf16 MFMA GEMM ----------------
// 5 blocks/batch: sub 0->(0,0) 1->(1,0) 2->(1,1) of G -> writes bf16 Gh
// + fp32 Gd for diagonal 16-tiles. sub 3..4 -> P0 row-blocks {0,1} (fp32).
__global__ __launch_bounds__(256)
void k1_gemm(const unsigned short* __restrict__ Xb,
             const unsigned short* __restrict__ Wg,
             float* __restrict__ Gd, unsigned short* __restrict__ Gh,
             float* __restrict__ P0)
{
    __shared__ unsigned short As[128 * 64];
    __shared__ unsigned short Bs[128 * 64];

    const int tid  = threadIdx.x;
    const int lane = tid & 63;
    const int wv   = tid >> 6;
    const int l16  = lane & 15;
    const int quad = lane >> 4;

    const int b   = blockIdx.x & 63;   // same-batch blocks -> same XCD
    const int sub = blockIdx.x >> 6;   // 0..4

    const unsigned short* xbB = Xb + (size_t)b * NT * NI;
    const unsigned short *aRows, *bRows;
    int bm = 0, bn = 0;
    if (sub < 3) {
        bm = (sub >= 1) ? 1 : 0;
        bn = (sub == 2) ? 1 : 0;
        aRows = xbB + (size_t)bm * 128 * NI;
        bRows = xbB + (size_t)bn * 128 * NI;
    } else {
        const int pb = sub - 3;
        bm = pb;
        aRows = xbB + (size_t)pb * 128 * NI;
        bRows = Wg + (size_t)b * NOBS * NI;
    }

    const int wm = (wv >> 1) * 64;
    const int wn = (wv & 1) * 64;

    f32x4 acc[4][4] = {};

    for (int kb = 0; kb < NI / 64; ++kb) {
        __syncthreads();
#pragma unroll
        for (int it = 0; it < 4; ++it) {
            const int s = it * 256 + tid;
            const int m = s >> 3, c = s & 7;
            const int slot = m * 64 + ((c ^ (m & 7)) * 8);
            const size_t goff = (size_t)m * NI + kb * 64 + c * 8;
            *(bf16x8*)&As[slot] = *(const bf16x8*)(aRows + goff);
            *(bf16x8*)&Bs[slot] = *(const bf16x8*)(bRows + goff);
        }
        __syncthreads();
#pragma unroll
        for (int ks = 0; ks < 2; ++ks) {
            const int q = ks * 4 + quad;
            bf16x8 af[4], bfr[4];
#pragma unroll
            for (int mt = 0; mt < 4; ++mt) {
                const int m = wm + mt * 16 + l16;
                af[mt] = *(const bf16x8*)&As[m * 64 + ((q ^ (m & 7)) * 8)];
            }
#pragma unroll
            for (int nt = 0; nt < 4; ++nt) {
                const int n = wn + nt * 16 + l16;
                bfr[nt] = *(const bf16x8*)&Bs[n * 64 + ((q ^ (n & 7)) * 8)];
            }
#pragma unroll
            for (int mt = 0; mt < 4; ++mt)
#pragma unroll
                for (int nt = 0; nt < 4; ++nt)
                    acc[mt][nt] = __builtin_amdgcn_mfma_f32_16x16x32_bf16(
                        af[mt], bfr[nt], acc[mt][nt], 0, 0, 0);
        }
    }

    if (sub < 3) {
        unsigned short* GhB = Gh + ((size_t)b << 16);
        float* GdB = Gd + ((size_t)b << 12);
#pragma unroll
        for (int mt = 0; mt < 4; ++mt)
#pragma unroll
            for (int nt = 0; nt < 4; ++nt) {
                const int gcol = bn * 128 + wn + nt * 16 + l16;
#pragma unroll
                for (int r = 0; r < 4; ++r) {
                    const int grow = bm * 128 + wm + mt * 16 + quad * 4 + r;
                    const float v = acc[mt][nt][r];
                    GhB[(size_t)grow * 256 + gcol] = f2bf(v);
                    if ((grow >> 4) == (gcol >> 4))
                        GdB[((grow >> 4) << 8) + ((grow & 15) << 4) + (gcol & 15)] = v;
                }
            }
    } else {
        float* Pb = P0 + (size_t)b * NT * NOBS + (size_t)bm * 128 * NOBS;
#pragma unroll
        for (int mt = 0; mt < 4; ++mt)
#pragma unroll
            for (int nt = 0; nt < 4; ++nt)
#pragma unroll
                for (int r = 0; r < 4; ++r)
                    Pb[(size_t)(wm + mt * 16 + quad * 4 + r) * NOBS
                       + wn + nt * 16 + l16] = acc[mt][nt][r];
    }
}

// ---------------- K2: single-wave MFMA scan (no barriers) ----------------
// block = 1 wave = (b, 32 j's) -> 256 blocks. Wave processes tiles T=0..15
// (16 t's each): load P0 C-frags; apply past chunk-pairs as K=32 MFMAs with
// register-resident bf16 B-frags (eta*y); odd tail via zero-masked A; dump
// to LDS; lanes 0-31 run the 16 serial sigmoid steps; build pair B-frag.
__global__ __launch_bounds__(64)
void k2_scan(const float* __restrict__ Gd, const unsigned short* __restrict__ Gh,
             const float* __restrict__ P0, float* __restrict__ out)
{
    __shared__ float gdiag[16 * 256];        // 16 KB [tile][u][v] fp32
    __shared__ unsigned short ybuf[32 * 32]; //  2 KB [k_local(32)][j(32)] eta*y bf16
    __shared__ float preS[16 * 33];          //  2.1 KB

    const int lane = threadIdx.x;            // 0..63
    const int l16  = lane & 15;
    const int quad = lane >> 4;

    const int b  = blockIdx.x & 63;          // same-batch blocks -> same XCD
    const int jg = blockIdx.x >> 6;          // 0..3

    const float* Pb = P0 + (size_t)b * NT * NOBS + jg * 32;
    const unsigned short* GhB = Gh + ((size_t)b << 16);
    float* ob = out + (size_t)b * NT * NOBS + jg * 32;

    // stage fp32 diag tiles (16 KB contiguous per b)
    {
        const f32x4* gs = (const f32x4*)(Gd + ((size_t)b << 12));
#pragma unroll
        for (int p = 0; p < 16; ++p)
            ((f32x4*)gdiag)[p * 64 + lane] = gs[p * 64 + lane];
    }

    bf16x8 Bf[8][2];                         // per chunk-pair B-frags (regs)

#pragma unroll
    for (int T = 0; T < 16; ++T) {
        // ---- load P0 C-frags: D[m=quad*4+r][n=l16]
        f32x4 acc[2];
#pragma unroll
        for (int nt = 0; nt < 2; ++nt)
#pragma unroll
            for (int r = 0; r < 4; ++r)
                acc[nt][r] = Pb[(size_t)(T * 16 + quad * 4 + r) * NOBS
                                + nt * 16 + l16];

        // ---- full chunk-pair updates (K=32 each)
#pragma unroll
        for (int p = 0; p < 8; ++p)
            if (p < (T >> 1)) {
                const bf16x8 A = *(const bf16x8*)(
                    GhB + (size_t)(T * 16 + l16) * 256 + p * 32 + quad * 8);
                acc[0] = __builtin_amdgcn_mfma_f32_16x16x32_bf16(
                    A, Bf[p][0], acc[0], 0, 0, 0);
                acc[1] = __builtin_amdgcn_mfma_f32_16x16x32_bf16(
                    A, Bf[p][1], acc[1], 0, 0, 0);
            }

        // ---- odd tail: chunk T-1 (ybuf rows 0..15), upper K-half zeroed via A
        if (T & 1) {
            union { bf16x8 v; unsigned int d[4]; } A, B0, B1;
#pragma unroll
            for (int q = 0; q < 4; ++q) { A.d[q] = 0; B0.d[q] = 0; B1.d[q] = 0; }
            if (quad < 2) {
                A.v = *(const bf16x8*)(
                    GhB + (size_t)(T * 16 + l16) * 256 + (T - 1) * 16 + quad * 8);
#pragma unroll
                for (int jj = 0; jj < 8; ++jj) {
                    const unsigned short y0 = ybuf[(quad * 8 + jj) * 32 + l16];
                    const unsigned short y1 = ybuf[(quad * 8 + jj) * 32 + 16 + l16];
                    B0.v[jj] = (short)y0;
                    B1.v[jj] = (short)y1;
                }
            }
            acc[0] = __builtin_amdgcn_mfma_f32_16x16x32_bf16(
                A.v, B0.v, acc[0], 0, 0, 0);
            acc[1] = __builtin_amdgcn_mfma_f32_16x16x32_bf16(
                A.v, B1.v, acc[1], 0, 0, 0);
        }

        // ---- dump C-frags to preS (stride 33 breaks conflicts)
#pragma unroll
        for (int nt = 0; nt < 2; ++nt)
#pragma unroll
            for (int r = 0; r < 4; ++r)
                preS[(quad * 4 + r) * 33 + nt * 16 + l16] = acc[nt][r];

        // ---- serial sigmoid scan, lanes 0..31 (j = lane)
        if (lane < 32) {
            const int j = lane;
            float pv[16];
#pragma unroll
            for (int u = 0; u < 16; ++u) pv[u] = preS[u * 33 + j];
            const float* gd = gdiag + T * 256;
            const int yrow = (T & 1) * 16;
#pragma unroll
            for (int u = 0; u < 16; ++u) {
                const float y = 1.f / (1.f + __expf(-pv[u]));
                ob[(size_t)(T * 16 + u) * NOBS + j] = y;
                const float e = ETA * y;
                ybuf[(yrow + u) * 32 + j] = f2bf(e);
#pragma unroll
                for (int v = u + 1; v < 16; ++v)
                    pv[v] = fmaf(e, gd[u * 16 + v], pv[v]);
            }
        }

        // ---- after odd tile: build pair P=(T>>1) B-frags from ybuf
        if (T & 1) {
            const int P = T >> 1;
            bf16x8 b0, b1;
#pragma unroll
            for (int jj = 0; jj < 8; ++jj) {
                b0[jj] = (short)ybuf[(quad * 8 + jj) * 32 + l16];
                b1[jj] = (short)ybuf[(quad * 8 + jj) * 32 + 16 + l16];
            }
            Bf[P][0] = b0;
            Bf[P][1] = b1;
        }
    }
}

extern "C" void kernel_launch(void* const* d_in, const int* in_sizes, int n_in,
                              void* d_out, int out_size, void* d_ws, size_t ws_size,
                              hipStream_t stream)
{
    const float* X   = (const float*)d_in[0];
    const float* Wi  = (const float*)d_in[1];
    const int*   obs = (const int*)d_in[2];
    float*       out = (float*)d_out;

    float*          Gd = (float*)d_ws;                                  //  1 MB
    float*          P0 = (float*)((char*)d_ws + (1u << 20));            //  8 MB
    unsigned short* Gh = (unsigned short*)((char*)d_ws + (9u << 20));   //  8 MB
    unsigned short* Xb = (unsigned short*)((char*)d_ws + (17u << 20));  // 16 MB
    unsigned short* Wg = (unsigned short*)((char*)d_ws + (33u << 20));  //  8 MB

    hipLaunchKernelGGL(k0_convert, dim3(3072), dim3(256), 0, stream,
                       X, Wi, obs, Xb, Wg);
    hipLaunchKernelGGL(k1_gemm, dim3(NB * 5), dim3(256), 0, stream,
                       Xb, Wg, Gd, Gh, P0);
    hipLaunchKernelGGL(k2_scan, dim3(NB * 4), dim3(64), 0, stream,
                       Gd, Gh, P0, out);
}